// Round 12
// baseline (600.226 us; speedup 1.0000x reference)
//
#include <hip/hip_runtime.h>
#include <hip/hip_fp16.h>

#define NN 100000
#define NE 1600000
#define NG 2000
#define DIM 256
#define NF 4
#define NBUK 196                 // ceil(NN / 512)
#define BSH 9                    // 512 nodes per bucket
#define BNODES 512
#define CHUNKS 512               // scatter blocks
#define CHUNK_E (NE / CHUNKS)    // 3125 edges per chunk
#define WCONV_BLK 128
#define PCAP 12288               // padded pair region per bucket (avg ~8163, 45 sigma)
#define SCAP 12288               // padded src-low9 region per bucket
#define COLBUF_CAP 12288
#define EMB_BLK1K ((NN * 64) / 1024)   // 6250 (1024-thread embed blocks)

using half8 = __attribute__((ext_vector_type(8))) _Float16;
using f32x4 = __attribute__((ext_vector_type(4))) float;

__device__ inline float4 h4_to_f4(uint2 v) {
    __half2 a = *reinterpret_cast<__half2*>(&v.x);
    __half2 b = *reinterpret_cast<__half2*>(&v.y);
    float2 fa = __half22float2(a);
    float2 fb = __half22float2(b);
    return make_float4(fa.x, fa.y, fb.x, fb.y);
}

__device__ inline uint2 f4_to_h4(float4 r) {
    __half2 a = __floats2half2_rn(r.x, r.y);
    __half2 b = __floats2half2_rn(r.z, r.w);
    uint2 o;
    o.x = *reinterpret_cast<uint*>(&a);
    o.y = *reinterpret_cast<uint*>(&b);
    return o;
}

__device__ inline void add8(float4& a0, float4& a1, uint4 u) {
    uint2 lo2; lo2.x = u.x; lo2.y = u.y;
    uint2 hi2; hi2.x = u.z; hi2.y = u.w;
    float4 lo = h4_to_f4(lo2);
    float4 hi = h4_to_f4(hi2);
    a0.x += lo.x; a0.y += lo.y; a0.z += lo.z; a0.w += lo.w;
    a1.x += hi.x; a1.y += hi.y; a1.z += hi.z; a1.w += hi.w;
}

// ---- K1 FUSED: dual bucket scatter (per-wave privatized hist + cursors) | wconv ----
__global__ void k_scatter2(const int* __restrict__ src, const int* __restrict__ dst,
                           int* __restrict__ pcnt, int* __restrict__ scnt,
                           uint* __restrict__ pbuf, ushort* __restrict__ sbuf,
                           const float* __restrict__ W1, ushort* __restrict__ Wt1) {
    __shared__ int h1[4][NBUK];
    __shared__ int h2[4][NBUK];
    int tid = threadIdx.x;
    if (blockIdx.x < CHUNKS) {
        int w = tid >> 6;
        int e0 = blockIdx.x * CHUNK_E;
        for (int i = tid; i < 4 * NBUK; i += 256) {
            (&h1[0][0])[i] = 0;
            (&h2[0][0])[i] = 0;
        }
        __syncthreads();
        // pass 1: per-wave histograms (no cross-wave LDS contention)
        for (int e = e0 + tid; e < e0 + CHUNK_E; e += 256) {
            atomicAdd(&h1[w][dst[e] >> BSH], 1);
            atomicAdd(&h2[w][src[e] >> BSH], 1);
        }
        __syncthreads();
        // reserve global ranges; convert per-wave counts into per-wave cursor bases
        if (tid < NBUK) {
            int t0 = h1[0][tid], t1 = h1[1][tid], t2 = h1[2][tid], t3 = h1[3][tid];
            int tot = t0 + t1 + t2 + t3;
            int base = tot > 0 ? atomicAdd(&pcnt[tid], tot) : 0;
            h1[0][tid] = base;
            h1[1][tid] = base + t0;
            h1[2][tid] = base + t0 + t1;
            h1[3][tid] = base + t0 + t1 + t2;
            int u0 = h2[0][tid], u1 = h2[1][tid], u2 = h2[2][tid], u3 = h2[3][tid];
            int stot = u0 + u1 + u2 + u3;
            int sbase = stot > 0 ? atomicAdd(&scnt[tid], stot) : 0;
            h2[0][tid] = sbase;
            h2[1][tid] = sbase + u0;
            h2[2][tid] = sbase + u0 + u1;
            h2[3][tid] = sbase + u0 + u1 + u2;
        }
        __syncthreads();
        // pass 2: scatter via per-wave cursors
        for (int e = e0 + tid; e < e0 + CHUNK_E; e += 256) {
            int d = dst[e];
            int s = src[e];
            int bb = d >> BSH;
            int r = atomicAdd(&h1[w][bb], 1);
            pbuf[bb * PCAP + r] = ((uint)(d & (BNODES - 1)) << 17) | (uint)s;
            int sb = s >> BSH;
            int r2 = atomicAdd(&h2[w][sb], 1);
            sbuf[sb * SCAP + r2] = (ushort)(s & (BNODES - 1));
        }
    } else {
        int idx = (blockIdx.x - CHUNKS) * 512 + tid * 2;  // 65536 total
        int k0 = idx >> 8, n0 = idx & 255;
        reinterpret_cast<__fp16*>(Wt1)[n0 * DIM + k0] = (__fp16)W1[idx];
        int idx1 = idx + 1;
        int k1 = idx1 >> 8, n1 = idx1 & 255;
        reinterpret_cast<__fp16*>(Wt1)[n1 * DIM + k1] = (__fp16)W1[idx1];
    }
}

// ---- K2 FUSED: exclusive scan of pair counts -> boff | per-bucket src count -> onorm ----
__global__ __launch_bounds__(256) void k_scan_onorm(const int* __restrict__ pcnt,
                                                    int* __restrict__ boff,
                                                    const int* __restrict__ scnt,
                                                    const ushort* __restrict__ sbuf,
                                                    float* __restrict__ onorm) {
    int t = threadIdx.x;
    if (blockIdx.x == 0) {
        __shared__ int sm[256];
        int v = (t < NBUK) ? pcnt[t] : 0;
        sm[t] = v;
        __syncthreads();
        for (int off = 1; off < 256; off <<= 1) {
            int u = (t >= off) ? sm[t - off] : 0;
            __syncthreads();
            sm[t] += u;
            __syncthreads();
        }
        if (t < NBUK) boff[t] = sm[t] - v;
        if (t == 255) boff[NBUK] = sm[255];
    } else {
        __shared__ int hist[BNODES];
        int b = blockIdx.x - 1;
        hist[t] = 0;
        hist[t + 256] = 0;
        __syncthreads();
        int n = scnt[b];
        const ushort* sp = sbuf + (size_t)b * SCAP;
        for (int i = t; i < n; i += 256) atomicAdd(&hist[sp[i]], 1);
        __syncthreads();
        int node0 = b << BSH;
#pragma unroll
        for (int k = t; k < BNODES; k += 256) {
            int node = node0 + k;
            if (node < NN) {
                int v = hist[k];
                onorm[node] = v > 0 ? rsqrtf((float)v) : 0.f;
            }
        }
    }
}

// ---- K3 FUSED: per-bucket CSR finalize (LDS hist+scan+scatter) | embed + onorm prescale ----
__global__ __launch_bounds__(1024) void k_bsort_embed(const uint* __restrict__ pbuf,
                                                      const int* __restrict__ boff,
                                                      int* __restrict__ col,
                                                      int* __restrict__ rowptr,
                                                      float* __restrict__ inorm,
                                                      const int* __restrict__ feat,
                                                      const float* __restrict__ emb,
                                                      const float* __restrict__ onorm,
                                                      ushort* __restrict__ h) {
    __shared__ int hist[BNODES];
    __shared__ int sc[BNODES];
    __shared__ int ex[BNODES];
    __shared__ int cur[BNODES];
    __shared__ int colbuf[COLBUF_CAP];
    int t = threadIdx.x;
    if (blockIdx.x < NBUK) {
        int b = blockIdx.x;
        int o0 = boff[b];
        int n = boff[b + 1] - o0;
        const uint* pp = pbuf + (size_t)b * PCAP;

        if (t < BNODES) hist[t] = 0;
        __syncthreads();
        for (int i = t; i < n; i += 1024) atomicAdd(&hist[pp[i] >> 17], 1);
        __syncthreads();
        int v = (t < BNODES) ? hist[t] : 0;
        if (t < BNODES) sc[t] = v;
        __syncthreads();
        for (int off = 1; off < BNODES; off <<= 1) {
            int u = (t < BNODES && t >= off) ? sc[t - off] : 0;
            __syncthreads();
            if (t < BNODES) sc[t] += u;
            __syncthreads();
        }
        if (t < BNODES) {
            ex[t] = sc[t] - v;
            cur[t] = 0;
            int node = (b << BSH) + t;
            if (node < NN) {
                rowptr[node] = o0 + ex[t];
                inorm[node] = v > 0 ? rsqrtf((float)v) : 0.f;
            }
        }
        if (b == NBUK - 1 && t == 0) rowptr[NN] = NE;
        __syncthreads();

        if (n <= COLBUF_CAP) {
            for (int i = t; i < n; i += 1024) {
                uint p = pp[i];
                int ld = p >> 17;
                int r = atomicAdd(&cur[ld], 1);
                colbuf[ex[ld] + r] = (int)(p & 0x1FFFF);
            }
            __syncthreads();
            for (int i = t; i < n; i += 1024) col[o0 + i] = colbuf[i];
        } else {  // statistically unreachable fallback
            for (int i = t; i < n; i += 1024) {
                uint p = pp[i];
                int ld = p >> 17;
                int r = atomicAdd(&cur[ld], 1);
                col[o0 + ex[ld] + r] = (int)(p & 0x1FFFF);
            }
        }
    } else {
        int idx = (blockIdx.x - NBUK) * 1024 + t;  // NN*64 total
        int node = idx >> 6;
        int g = idx & 63;
        if (node >= NN) return;
        const int4 f = *reinterpret_cast<const int4*>(feat + node * 4);
        const float4* emb4 = reinterpret_cast<const float4*>(emb);
        float4 a = emb4[(long)f.x * 64 + g];
        float4 b = emb4[(long)f.y * 64 + g];
        float4 c = emb4[(long)f.z * 64 + g];
        float4 d = emb4[(long)f.w * 64 + g];
        float scn = onorm[node];
        float4 r;
        r.x = (a.x + b.x + c.x + d.x) * scn;
        r.y = (a.y + b.y + c.y + d.y) * scn;
        r.z = (a.z + b.z + c.z + d.z) * scn;
        r.w = (a.w + b.w + c.w + d.w) * scn;
        reinterpret_cast<uint2*>(h)[(long)node * 64 + g] = f4_to_h4(r);
    }
}

// ---------------- aggregation: one wave per dst node ----------------
// MODE 0: hout = relu(acc * inorm) * onorm ; MODE 1: hout = acc * inorm
template <int MODE>
__global__ void k_agg(const int* __restrict__ rowptr, const int* __restrict__ col,
                      const ushort* __restrict__ hin, const float* __restrict__ inorm,
                      const float* __restrict__ onorm, ushort* __restrict__ hout) {
    int wid = (blockIdx.x * blockDim.x + threadIdx.x) >> 6;
    int lane = threadIdx.x & 63;
    if (wid >= NN) return;
    int half = lane >> 5;
    int l32 = lane & 31;
    int e0 = rowptr[wid];
    int e1 = rowptr[wid + 1];
    const uint4* hin4 = reinterpret_cast<const uint4*>(hin);
    float4 aA0 = {0,0,0,0}, aA1 = {0,0,0,0};
    float4 aB0 = {0,0,0,0}, aB1 = {0,0,0,0};
    int e = e0;
    for (; e + 8 <= e1; e += 8) {
        int s0 = col[e + 0 + half];
        int s1 = col[e + 2 + half];
        int s2 = col[e + 4 + half];
        int s3 = col[e + 6 + half];
        uint4 u0 = hin4[(long)s0 * 32 + l32];
        uint4 u1 = hin4[(long)s1 * 32 + l32];
        uint4 u2 = hin4[(long)s2 * 32 + l32];
        uint4 u3 = hin4[(long)s3 * 32 + l32];
        add8(aA0, aA1, u0);
        add8(aB0, aB1, u1);
        add8(aA0, aA1, u2);
        add8(aB0, aB1, u3);
    }
    for (; e < e1; e += 2) {
        int idx = e + half;
        if (idx < e1) {
            int s = col[idx];
            uint4 u = hin4[(long)s * 32 + l32];
            add8(aA0, aA1, u);
        }
    }
    float f[8];
    f[0] = aA0.x + aB0.x; f[1] = aA0.y + aB0.y; f[2] = aA0.z + aB0.z; f[3] = aA0.w + aB0.w;
    f[4] = aA1.x + aB1.x; f[5] = aA1.y + aB1.y; f[6] = aA1.z + aB1.z; f[7] = aA1.w + aB1.w;
#pragma unroll
    for (int j = 0; j < 8; ++j) f[j] += __shfl_xor(f[j], 32);

    float scn = inorm[wid];
    float4 r0, r1;
    if (MODE == 0) {
        float on = onorm[wid];
        r0.x = fmaxf(f[0] * scn, 0.f) * on;
        r0.y = fmaxf(f[1] * scn, 0.f) * on;
        r0.z = fmaxf(f[2] * scn, 0.f) * on;
        r0.w = fmaxf(f[3] * scn, 0.f) * on;
        r1.x = fmaxf(f[4] * scn, 0.f) * on;
        r1.y = fmaxf(f[5] * scn, 0.f) * on;
        r1.z = fmaxf(f[6] * scn, 0.f) * on;
        r1.w = fmaxf(f[7] * scn, 0.f) * on;
    } else {
        r0.x = f[0] * scn; r0.y = f[1] * scn; r0.z = f[2] * scn; r0.w = f[3] * scn;
        r1.x = f[4] * scn; r1.y = f[5] * scn; r1.z = f[6] * scn; r1.w = f[7] * scn;
    }
    if (half == 0) {
        uint2 lo = f4_to_h4(r0);
        uint2 hi = f4_to_h4(r1);
        uint4 o; o.x = lo.x; o.y = lo.y; o.z = hi.x; o.w = hi.y;
        reinterpret_cast<uint4*>(hout)[(long)wid * 32 + l32] = o;
    }
}

// ---------------- MFMA GEMM: y[NN,256] = x[NN,256] @ W[256,256] ----------------
__global__ __launch_bounds__(512, 2) void k_gemm(const ushort* __restrict__ x,
                                                 const ushort* __restrict__ Wt,
                                                 ushort* __restrict__ y) {
    __shared__ char wl[131072];
    int tid = threadIdx.x;
    const uint4* Wt4 = reinterpret_cast<const uint4*>(Wt);
#pragma unroll
    for (int it = 0; it < 16; ++it) {
        int chunk = it * 512 + tid;      // 0..8191 16B-chunks
        int n = chunk >> 5;              // row 0..255
        int c16 = chunk & 31;
        uint4 v = Wt4[chunk];
        int off = ((n << 9) + (c16 << 4)) ^ ((n & 7) << 4);
        *reinterpret_cast<uint4*>(&wl[off]) = v;
    }
    __syncthreads();

    int w = tid >> 6;
    int l = tid & 63;
    int wrow = blockIdx.x * 384 + w * 48;
    int lrow = l & 15;
    int lk = l >> 4;

    f32x4 acc[3][16];
#pragma unroll
    for (int m = 0; m < 3; ++m)
#pragma unroll
        for (int n = 0; n < 16; ++n) acc[m][n] = {0.f, 0.f, 0.f, 0.f};

    const char* xb = reinterpret_cast<const char*>(x);
    int r0 = wrow + lrow;
    int r1 = r0 + 16;
    int r2 = r0 + 32;
    r0 = r0 < NN ? r0 : NN - 1;
    r1 = r1 < NN ? r1 : NN - 1;
    r2 = r2 < NN ? r2 : NN - 1;

#pragma unroll
    for (int ks = 0; ks < DIM; ks += 32) {
        long kbyte = (long)(ks + lk * 8) * 2;
        half8 a0 = *reinterpret_cast<const half8*>(xb + (long)r0 * 512 + kbyte);
        half8 a1 = *reinterpret_cast<const half8*>(xb + (long)r1 * 512 + kbyte);
        half8 a2 = *reinterpret_cast<const half8*>(xb + (long)r2 * 512 + kbyte);
#pragma unroll
        for (int fn = 0; fn < 16; ++fn) {
            int n = fn * 16 + lrow;
            int off = ((n << 9) + (int)kbyte) ^ ((n & 7) << 4);
            half8 bb = *reinterpret_cast<const half8*>(&wl[off]);
            acc[0][fn] = __builtin_amdgcn_mfma_f32_16x16x32_f16(a0, bb, acc[0][fn], 0, 0, 0);
            acc[1][fn] = __builtin_amdgcn_mfma_f32_16x16x32_f16(a1, bb, acc[1][fn], 0, 0, 0);
            acc[2][fn] = __builtin_amdgcn_mfma_f32_16x16x32_f16(a2, bb, acc[2][fn], 0, 0, 0);
        }
    }

    __fp16* yh = reinterpret_cast<__fp16*>(y);
#pragma unroll
    for (int m = 0; m < 3; ++m) {
        int rbase = wrow + m * 16 + lk * 4;
#pragma unroll
        for (int fn = 0; fn < 16; ++fn) {
            int colc = fn * 16 + lrow;
#pragma unroll
            for (int r = 0; r < 4; ++r) {
                int row = rbase + r;
                if (row < NN) yh[(long)row * DIM + colc] = (__fp16)acc[m][fn][r];
            }
        }
    }
}

// ---- FUSED pool + mini-GEMM: out[NG,256] = pool(h)[NG,256] @ W2 (fp32, W2 L2-resident) ----
__device__ inline int lbound(const int* __restrict__ a, int n, int v) {
    int lo = 0, hi = n;
    while (lo < hi) {
        int m = (lo + hi) >> 1;
        if (a[m] < v) lo = m + 1; else hi = m;
    }
    return lo;
}

__global__ __launch_bounds__(256) void k_poolgemm(const ushort* __restrict__ h,
                                                  const int* __restrict__ gids,
                                                  const float* __restrict__ W2,
                                                  float* __restrict__ out) {
    __shared__ float Pl[8][DIM];
    __shared__ int bounds[9];
    int t = threadIdx.x;
    int g0 = blockIdx.x * 8;
    if (t < 9) bounds[t] = lbound(gids, NN, g0 + t);
    __syncthreads();
    const __fp16* hh = reinterpret_cast<const __fp16*>(h);
#pragma unroll
    for (int r = 0; r < 8; ++r) {
        float acc = 0.f;
        for (int nd = bounds[r]; nd < bounds[r + 1]; ++nd)
            acc += (float)hh[(long)nd * DIM + t];
        Pl[r][t] = acc;
    }
    __syncthreads();
    float acc[8];
#pragma unroll
    for (int r = 0; r < 8; ++r) acc[r] = 0.f;
    for (int k = 0; k < DIM; ++k) {
        float w = W2[(long)k * DIM + t];
#pragma unroll
        for (int r = 0; r < 8; ++r) acc[r] += Pl[r][k] * w;
    }
#pragma unroll
    for (int r = 0; r < 8; ++r) out[(long)(g0 + r) * DIM + t] = acc[r];
}

extern "C" void kernel_launch(void* const* d_in, const int* in_sizes, int n_in,
                              void* d_out, int out_size, void* d_ws, size_t ws_size,
                              hipStream_t stream) {
    const int* feature = (const int*)d_in[0];
    const int* src = (const int*)d_in[1];
    const int* dst = (const int*)d_in[2];
    const int* gids = (const int*)d_in[3];
    const float* emb = (const float*)d_in[4];
    const float* W1 = (const float*)d_in[5];
    const float* W2 = (const float*)d_in[6];
    float* out = (float*)d_out;

    // workspace carve (all 16B aligned)
    char* p = (char*)d_ws;
    ushort* hA = (ushort*)p;            p += (size_t)NN * DIM * 2;
    ushort* hB = (ushort*)p;            p += (size_t)NN * DIM * 2;
    ushort* Wt1 = (ushort*)p;           p += (size_t)DIM * DIM * 2;
    float* onorm = (float*)p;           p += (size_t)NN * 4;
    float* inorm = (float*)p;           p += (size_t)NN * 4;
    int* rowptr = (int*)p;              p += (size_t)(NN + 4) * 4;
    int* colidx = (int*)p;              p += (size_t)NE * 4;
    int* pcnt = (int*)p;                p += (size_t)NBUK * 4;        // zeroed
    int* scnt = (int*)p;                p += (size_t)NBUK * 4;        // zeroed (adjacent)
    int* boff = (int*)p;                p += (size_t)(NBUK + 4) * 4;
    uint* pbuf = (uint*)p;              p += (size_t)NBUK * PCAP * 4;
    ushort* sbuf = (ushort*)p;          p += (size_t)NBUK * SCAP * 2;

    // zero the two 196-counter arrays (adjacent)
    hipMemsetAsync(pcnt, 0, (size_t)2 * NBUK * 4, stream);

    // K1: dual bucket scatter | W1 -> Wt1
    k_scatter2<<<CHUNKS + WCONV_BLK, 256, 0, stream>>>(src, dst, pcnt, scnt,
                                                       pbuf, sbuf, W1, Wt1);
    // K2: boff scan | src counts -> onorm
    k_scan_onorm<<<1 + NBUK, 256, 0, stream>>>(pcnt, boff, scnt, sbuf, onorm);
    // K3: per-bucket CSR finalize | embed (+onorm prescale)
    k_bsort_embed<<<NBUK + EMB_BLK1K, 1024, 0, stream>>>(pbuf, boff, colidx, rowptr, inorm,
                                                         feature, emb, onorm, hA);

    const int aggGrid = (NN * 64 + 255) / 256;
    const int gemmGrid = (NN + 383) / 384;
    // layer 0 (no W): hB = relu(agg(hA) * inorm) * onorm
    k_agg<0><<<aggGrid, 256, 0, stream>>>(rowptr, colidx, hA, inorm, onorm, hB);
    // layer 1: hA = hB @ W1 ; hB = relu(agg(hA) * inorm) * onorm
    k_gemm<<<gemmGrid, 512, 0, stream>>>(hB, Wt1, hA);
    k_agg<0><<<aggGrid, 256, 0, stream>>>(rowptr, colidx, hA, inorm, onorm, hB);
    // layer 2 (W2 hoisted past agg+pool by linearity): hA = agg(hB) * inorm
    k_agg<1><<<aggGrid, 256, 0, stream>>>(rowptr, colidx, hB, inorm, onorm, hA);
    // out = pool(hA) @ W2   (fused)
    k_poolgemm<<<NG / 8, 256, 0, stream>>>(hA, gids, W2, out);
}

// Round 13
// 523.873 us; speedup vs baseline: 1.1457x; 1.1457x over previous
//
#include <hip/hip_runtime.h>
#include <hip/hip_fp16.h>

#define NN 100000
#define NE 1600000
#define NG 2000
#define DIM 256
#define NF 4
#define NBUK 196                 // ceil(NN / 512)
#define BSH 9                    // 512 nodes per bucket
#define BNODES 512
#define CHUNKS 512               // scatter blocks
#define CHUNK_E (NE / CHUNKS)    // 3125 edges per chunk
#define WCONV_BLK 128
#define PCAP 12288               // padded pair region per bucket (avg ~8163, 45 sigma)
#define SCAP 12288               // padded src-low9 region per bucket
#define COLBUF_CAP 12288
#define EMB_BLK1K ((NN * 64) / 1024)   // 6250 (1024-thread embed blocks)

using half8 = __attribute__((ext_vector_type(8))) _Float16;
using f32x4 = __attribute__((ext_vector_type(4))) float;

__device__ inline float4 h4_to_f4(uint2 v) {
    __half2 a = *reinterpret_cast<__half2*>(&v.x);
    __half2 b = *reinterpret_cast<__half2*>(&v.y);
    float2 fa = __half22float2(a);
    float2 fb = __half22float2(b);
    return make_float4(fa.x, fa.y, fb.x, fb.y);
}

__device__ inline uint2 f4_to_h4(float4 r) {
    __half2 a = __floats2half2_rn(r.x, r.y);
    __half2 b = __floats2half2_rn(r.z, r.w);
    uint2 o;
    o.x = *reinterpret_cast<uint*>(&a);
    o.y = *reinterpret_cast<uint*>(&b);
    return o;
}

__device__ inline void add8(float4& a0, float4& a1, uint4 u) {
    uint2 lo2; lo2.x = u.x; lo2.y = u.y;
    uint2 hi2; hi2.x = u.z; hi2.y = u.w;
    float4 lo = h4_to_f4(lo2);
    float4 hi = h4_to_f4(hi2);
    a0.x += lo.x; a0.y += lo.y; a0.z += lo.z; a0.w += lo.w;
    a1.x += hi.x; a1.y += hi.y; a1.z += hi.z; a1.w += hi.w;
}

// ---- K1 FUSED: dual bucket scatter (per-wave privatized hist + cursors) | wconv ----
__global__ void k_scatter2(const int* __restrict__ src, const int* __restrict__ dst,
                           int* __restrict__ pcnt, int* __restrict__ scnt,
                           uint* __restrict__ pbuf, ushort* __restrict__ sbuf,
                           const float* __restrict__ W1, ushort* __restrict__ Wt1) {
    __shared__ int h1[4][NBUK];
    __shared__ int h2[4][NBUK];
    int tid = threadIdx.x;
    if (blockIdx.x < CHUNKS) {
        int w = tid >> 6;
        int e0 = blockIdx.x * CHUNK_E;
        for (int i = tid; i < 4 * NBUK; i += 256) {
            (&h1[0][0])[i] = 0;
            (&h2[0][0])[i] = 0;
        }
        __syncthreads();
        // pass 1: per-wave histograms (no cross-wave LDS contention)
        for (int e = e0 + tid; e < e0 + CHUNK_E; e += 256) {
            atomicAdd(&h1[w][dst[e] >> BSH], 1);
            atomicAdd(&h2[w][src[e] >> BSH], 1);
        }
        __syncthreads();
        // reserve global ranges; convert per-wave counts into per-wave cursor bases
        if (tid < NBUK) {
            int t0 = h1[0][tid], t1 = h1[1][tid], t2 = h1[2][tid], t3 = h1[3][tid];
            int tot = t0 + t1 + t2 + t3;
            int base = tot > 0 ? atomicAdd(&pcnt[tid], tot) : 0;
            h1[0][tid] = base;
            h1[1][tid] = base + t0;
            h1[2][tid] = base + t0 + t1;
            h1[3][tid] = base + t0 + t1 + t2;
            int u0 = h2[0][tid], u1 = h2[1][tid], u2 = h2[2][tid], u3 = h2[3][tid];
            int stot = u0 + u1 + u2 + u3;
            int sbase = stot > 0 ? atomicAdd(&scnt[tid], stot) : 0;
            h2[0][tid] = sbase;
            h2[1][tid] = sbase + u0;
            h2[2][tid] = sbase + u0 + u1;
            h2[3][tid] = sbase + u0 + u1 + u2;
        }
        __syncthreads();
        // pass 2: scatter via per-wave cursors
        for (int e = e0 + tid; e < e0 + CHUNK_E; e += 256) {
            int d = dst[e];
            int s = src[e];
            int bb = d >> BSH;
            int r = atomicAdd(&h1[w][bb], 1);
            pbuf[bb * PCAP + r] = ((uint)(d & (BNODES - 1)) << 17) | (uint)s;
            int sb = s >> BSH;
            int r2 = atomicAdd(&h2[w][sb], 1);
            sbuf[sb * SCAP + r2] = (ushort)(s & (BNODES - 1));
        }
    } else {
        int idx = (blockIdx.x - CHUNKS) * 512 + tid * 2;  // 65536 total
        int k0 = idx >> 8, n0 = idx & 255;
        reinterpret_cast<__fp16*>(Wt1)[n0 * DIM + k0] = (__fp16)W1[idx];
        int idx1 = idx + 1;
        int k1 = idx1 >> 8, n1 = idx1 & 255;
        reinterpret_cast<__fp16*>(Wt1)[n1 * DIM + k1] = (__fp16)W1[idx1];
    }
}

// ---- K2 FUSED: exclusive scan of pair counts -> boff | per-bucket src count -> onorm ----
__global__ __launch_bounds__(256) void k_scan_onorm(const int* __restrict__ pcnt,
                                                    int* __restrict__ boff,
                                                    const int* __restrict__ scnt,
                                                    const ushort* __restrict__ sbuf,
                                                    float* __restrict__ onorm) {
    int t = threadIdx.x;
    if (blockIdx.x == 0) {
        __shared__ int sm[256];
        int v = (t < NBUK) ? pcnt[t] : 0;
        sm[t] = v;
        __syncthreads();
        for (int off = 1; off < 256; off <<= 1) {
            int u = (t >= off) ? sm[t - off] : 0;
            __syncthreads();
            sm[t] += u;
            __syncthreads();
        }
        if (t < NBUK) boff[t] = sm[t] - v;
        if (t == 255) boff[NBUK] = sm[255];
    } else {
        __shared__ int hist[BNODES];
        int b = blockIdx.x - 1;
        hist[t] = 0;
        hist[t + 256] = 0;
        __syncthreads();
        int n = scnt[b];
        const ushort* sp = sbuf + (size_t)b * SCAP;
        for (int i = t; i < n; i += 256) atomicAdd(&hist[sp[i]], 1);
        __syncthreads();
        int node0 = b << BSH;
#pragma unroll
        for (int k = t; k < BNODES; k += 256) {
            int node = node0 + k;
            if (node < NN) {
                int v = hist[k];
                onorm[node] = v > 0 ? rsqrtf((float)v) : 0.f;
            }
        }
    }
}

// ---- K3 FUSED: per-bucket CSR finalize (LDS hist+scan+scatter) | embed + onorm prescale ----
__global__ __launch_bounds__(1024) void k_bsort_embed(const uint* __restrict__ pbuf,
                                                      const int* __restrict__ boff,
                                                      int* __restrict__ col,
                                                      int* __restrict__ rowptr,
                                                      float* __restrict__ inorm,
                                                      const int* __restrict__ feat,
                                                      const float* __restrict__ emb,
                                                      const float* __restrict__ onorm,
                                                      ushort* __restrict__ h) {
    __shared__ int hist[BNODES];
    __shared__ int sc[BNODES];
    __shared__ int ex[BNODES];
    __shared__ int cur[BNODES];
    __shared__ int colbuf[COLBUF_CAP];
    int t = threadIdx.x;
    if (blockIdx.x < NBUK) {
        int b = blockIdx.x;
        int o0 = boff[b];
        int n = boff[b + 1] - o0;
        const uint* pp = pbuf + (size_t)b * PCAP;

        if (t < BNODES) hist[t] = 0;
        __syncthreads();
        for (int i = t; i < n; i += 1024) atomicAdd(&hist[pp[i] >> 17], 1);
        __syncthreads();
        int v = (t < BNODES) ? hist[t] : 0;
        if (t < BNODES) sc[t] = v;
        __syncthreads();
        for (int off = 1; off < BNODES; off <<= 1) {
            int u = (t < BNODES && t >= off) ? sc[t - off] : 0;
            __syncthreads();
            if (t < BNODES) sc[t] += u;
            __syncthreads();
        }
        if (t < BNODES) {
            ex[t] = sc[t] - v;
            cur[t] = 0;
            int node = (b << BSH) + t;
            if (node < NN) {
                rowptr[node] = o0 + ex[t];
                inorm[node] = v > 0 ? rsqrtf((float)v) : 0.f;
            }
        }
        if (b == NBUK - 1 && t == 0) rowptr[NN] = NE;
        __syncthreads();

        if (n <= COLBUF_CAP) {
            for (int i = t; i < n; i += 1024) {
                uint p = pp[i];
                int ld = p >> 17;
                int r = atomicAdd(&cur[ld], 1);
                colbuf[ex[ld] + r] = (int)(p & 0x1FFFF);
            }
            __syncthreads();
            for (int i = t; i < n; i += 1024) col[o0 + i] = colbuf[i];
        } else {  // statistically unreachable fallback
            for (int i = t; i < n; i += 1024) {
                uint p = pp[i];
                int ld = p >> 17;
                int r = atomicAdd(&cur[ld], 1);
                col[o0 + ex[ld] + r] = (int)(p & 0x1FFFF);
            }
        }
    } else {
        int idx = (blockIdx.x - NBUK) * 1024 + t;  // NN*64 total
        int node = idx >> 6;
        int g = idx & 63;
        if (node >= NN) return;
        const int4 f = *reinterpret_cast<const int4*>(feat + node * 4);
        const float4* emb4 = reinterpret_cast<const float4*>(emb);
        float4 a = emb4[(long)f.x * 64 + g];
        float4 b = emb4[(long)f.y * 64 + g];
        float4 c = emb4[(long)f.z * 64 + g];
        float4 d = emb4[(long)f.w * 64 + g];
        float scn = onorm[node];
        float4 r;
        r.x = (a.x + b.x + c.x + d.x) * scn;
        r.y = (a.y + b.y + c.y + d.y) * scn;
        r.z = (a.z + b.z + c.z + d.z) * scn;
        r.w = (a.w + b.w + c.w + d.w) * scn;
        reinterpret_cast<uint2*>(h)[(long)node * 64 + g] = f4_to_h4(r);
    }
}

// ---------------- aggregation: one wave per dst node ----------------
// MODE 0: hout = relu(acc * inorm) * onorm ; MODE 1: hout = acc * inorm
template <int MODE>
__global__ void k_agg(const int* __restrict__ rowptr, const int* __restrict__ col,
                      const ushort* __restrict__ hin, const float* __restrict__ inorm,
                      const float* __restrict__ onorm, ushort* __restrict__ hout) {
    int wid = (blockIdx.x * blockDim.x + threadIdx.x) >> 6;
    int lane = threadIdx.x & 63;
    if (wid >= NN) return;
    int half = lane >> 5;
    int l32 = lane & 31;
    int e0 = rowptr[wid];
    int e1 = rowptr[wid + 1];
    const uint4* hin4 = reinterpret_cast<const uint4*>(hin);
    float4 aA0 = {0,0,0,0}, aA1 = {0,0,0,0};
    float4 aB0 = {0,0,0,0}, aB1 = {0,0,0,0};
    int e = e0;
    for (; e + 8 <= e1; e += 8) {
        int s0 = col[e + 0 + half];
        int s1 = col[e + 2 + half];
        int s2 = col[e + 4 + half];
        int s3 = col[e + 6 + half];
        uint4 u0 = hin4[(long)s0 * 32 + l32];
        uint4 u1 = hin4[(long)s1 * 32 + l32];
        uint4 u2 = hin4[(long)s2 * 32 + l32];
        uint4 u3 = hin4[(long)s3 * 32 + l32];
        add8(aA0, aA1, u0);
        add8(aB0, aB1, u1);
        add8(aA0, aA1, u2);
        add8(aB0, aB1, u3);
    }
    for (; e < e1; e += 2) {
        int idx = e + half;
        if (idx < e1) {
            int s = col[idx];
            uint4 u = hin4[(long)s * 32 + l32];
            add8(aA0, aA1, u);
        }
    }
    float f[8];
    f[0] = aA0.x + aB0.x; f[1] = aA0.y + aB0.y; f[2] = aA0.z + aB0.z; f[3] = aA0.w + aB0.w;
    f[4] = aA1.x + aB1.x; f[5] = aA1.y + aB1.y; f[6] = aA1.z + aB1.z; f[7] = aA1.w + aB1.w;
#pragma unroll
    for (int j = 0; j < 8; ++j) f[j] += __shfl_xor(f[j], 32);

    float scn = inorm[wid];
    float4 r0, r1;
    if (MODE == 0) {
        float on = onorm[wid];
        r0.x = fmaxf(f[0] * scn, 0.f) * on;
        r0.y = fmaxf(f[1] * scn, 0.f) * on;
        r0.z = fmaxf(f[2] * scn, 0.f) * on;
        r0.w = fmaxf(f[3] * scn, 0.f) * on;
        r1.x = fmaxf(f[4] * scn, 0.f) * on;
        r1.y = fmaxf(f[5] * scn, 0.f) * on;
        r1.z = fmaxf(f[6] * scn, 0.f) * on;
        r1.w = fmaxf(f[7] * scn, 0.f) * on;
    } else {
        r0.x = f[0] * scn; r0.y = f[1] * scn; r0.z = f[2] * scn; r0.w = f[3] * scn;
        r1.x = f[4] * scn; r1.y = f[5] * scn; r1.z = f[6] * scn; r1.w = f[7] * scn;
    }
    if (half == 0) {
        uint2 lo = f4_to_h4(r0);
        uint2 hi = f4_to_h4(r1);
        uint4 o; o.x = lo.x; o.y = lo.y; o.z = hi.x; o.w = hi.y;
        reinterpret_cast<uint4*>(hout)[(long)wid * 32 + l32] = o;
    }
}

// ---------------- MFMA GEMM: y[NN,256] = x[NN,256] @ W[256,256] ----------------
__global__ __launch_bounds__(512, 2) void k_gemm(const ushort* __restrict__ x,
                                                 const ushort* __restrict__ Wt,
                                                 ushort* __restrict__ y) {
    __shared__ char wl[131072];
    int tid = threadIdx.x;
    const uint4* Wt4 = reinterpret_cast<const uint4*>(Wt);
#pragma unroll
    for (int it = 0; it < 16; ++it) {
        int chunk = it * 512 + tid;      // 0..8191 16B-chunks
        int n = chunk >> 5;              // row 0..255
        int c16 = chunk & 31;
        uint4 v = Wt4[chunk];
        int off = ((n << 9) + (c16 << 4)) ^ ((n & 7) << 4);
        *reinterpret_cast<uint4*>(&wl[off]) = v;
    }
    __syncthreads();

    int w = tid >> 6;
    int l = tid & 63;
    int wrow = blockIdx.x * 384 + w * 48;
    int lrow = l & 15;
    int lk = l >> 4;

    f32x4 acc[3][16];
#pragma unroll
    for (int m = 0; m < 3; ++m)
#pragma unroll
        for (int n = 0; n < 16; ++n) acc[m][n] = {0.f, 0.f, 0.f, 0.f};

    const char* xb = reinterpret_cast<const char*>(x);
    int r0 = wrow + lrow;
    int r1 = r0 + 16;
    int r2 = r0 + 32;
    r0 = r0 < NN ? r0 : NN - 1;
    r1 = r1 < NN ? r1 : NN - 1;
    r2 = r2 < NN ? r2 : NN - 1;

#pragma unroll
    for (int ks = 0; ks < DIM; ks += 32) {
        long kbyte = (long)(ks + lk * 8) * 2;
        half8 a0 = *reinterpret_cast<const half8*>(xb + (long)r0 * 512 + kbyte);
        half8 a1 = *reinterpret_cast<const half8*>(xb + (long)r1 * 512 + kbyte);
        half8 a2 = *reinterpret_cast<const half8*>(xb + (long)r2 * 512 + kbyte);
#pragma unroll
        for (int fn = 0; fn < 16; ++fn) {
            int n = fn * 16 + lrow;
            int off = ((n << 9) + (int)kbyte) ^ ((n & 7) << 4);
            half8 bb = *reinterpret_cast<const half8*>(&wl[off]);
            acc[0][fn] = __builtin_amdgcn_mfma_f32_16x16x32_f16(a0, bb, acc[0][fn], 0, 0, 0);
            acc[1][fn] = __builtin_amdgcn_mfma_f32_16x16x32_f16(a1, bb, acc[1][fn], 0, 0, 0);
            acc[2][fn] = __builtin_amdgcn_mfma_f32_16x16x32_f16(a2, bb, acc[2][fn], 0, 0, 0);
        }
    }

    __fp16* yh = reinterpret_cast<__fp16*>(y);
#pragma unroll
    for (int m = 0; m < 3; ++m) {
        int rbase = wrow + m * 16 + lk * 4;
#pragma unroll
        for (int fn = 0; fn < 16; ++fn) {
            int colc = fn * 16 + lrow;
#pragma unroll
            for (int r = 0; r < 4; ++r) {
                int row = rbase + r;
                if (row < NN) yh[(long)row * DIM + colc] = (__fp16)acc[m][fn][r];
            }
        }
    }
}

// ---------------- per-graph sum pooling (graph_ids sorted) -> P fp32 ----------------
__device__ inline int lbound(const int* __restrict__ a, int n, int v) {
    int lo = 0, hi = n;
    while (lo < hi) {
        int m = (lo + hi) >> 1;
        if (a[m] < v) lo = m + 1; else hi = m;
    }
    return lo;
}

__global__ __launch_bounds__(256) void k_pool(const ushort* __restrict__ h,
                                              const int* __restrict__ gids,
                                              float* __restrict__ P) {
    int g = blockIdx.x;
    int t = threadIdx.x;
    int lo = lbound(gids, NN, g);
    int hi = lbound(gids, NN, g + 1);
    const __fp16* hh = reinterpret_cast<const __fp16*>(h);
    float acc = 0.f;
    for (int nd = lo; nd < hi; ++nd) acc += (float)hh[(long)nd * DIM + t];
    P[(long)g * DIM + t] = acc;
}

// ---------------- mini-GEMM: out[NG,256] = P[NG,256] @ W2[256,256] (fp32) ----------------
__global__ __launch_bounds__(256) void k_pgemm(const float* __restrict__ P,
                                               const float* __restrict__ W2,
                                               float* __restrict__ out) {
    __shared__ float Pl[8][DIM];
    int t = threadIdx.x;
    int rbase = blockIdx.x * 8;
#pragma unroll
    for (int r = 0; r < 8; ++r) Pl[r][t] = P[(long)(rbase + r) * DIM + t];
    __syncthreads();
    float acc[8];
#pragma unroll
    for (int r = 0; r < 8; ++r) acc[r] = 0.f;
    for (int k = 0; k < DIM; ++k) {
        float w = W2[(long)k * DIM + t];
#pragma unroll
        for (int r = 0; r < 8; ++r) acc[r] += Pl[r][k] * w;
    }
#pragma unroll
    for (int r = 0; r < 8; ++r) out[(long)(rbase + r) * DIM + t] = acc[r];
}

extern "C" void kernel_launch(void* const* d_in, const int* in_sizes, int n_in,
                              void* d_out, int out_size, void* d_ws, size_t ws_size,
                              hipStream_t stream) {
    const int* feature = (const int*)d_in[0];
    const int* src = (const int*)d_in[1];
    const int* dst = (const int*)d_in[2];
    const int* gids = (const int*)d_in[3];
    const float* emb = (const float*)d_in[4];
    const float* W1 = (const float*)d_in[5];
    const float* W2 = (const float*)d_in[6];
    float* out = (float*)d_out;

    // workspace carve (all 16B aligned)
    char* p = (char*)d_ws;
    ushort* hA = (ushort*)p;            p += (size_t)NN * DIM * 2;
    ushort* hB = (ushort*)p;            p += (size_t)NN * DIM * 2;
    ushort* Wt1 = (ushort*)p;           p += (size_t)DIM * DIM * 2;
    float* onorm = (float*)p;           p += (size_t)NN * 4;
    float* inorm = (float*)p;           p += (size_t)NN * 4;
    int* rowptr = (int*)p;              p += (size_t)(NN + 4) * 4;
    int* colidx = (int*)p;              p += (size_t)NE * 4;
    int* pcnt = (int*)p;                p += (size_t)NBUK * 4;        // zeroed
    int* scnt = (int*)p;                p += (size_t)NBUK * 4;        // zeroed (adjacent)
    int* boff = (int*)p;                p += (size_t)(NBUK + 4) * 4;
    uint* pbuf = (uint*)p;              p += (size_t)NBUK * PCAP * 4;
    ushort* sbuf = (ushort*)p;          p += (size_t)NBUK * SCAP * 2;
    float* Pbuf = (float*)p;            p += (size_t)NG * DIM * 4;

    // zero the two 196-counter arrays (adjacent)
    hipMemsetAsync(pcnt, 0, (size_t)2 * NBUK * 4, stream);

    // K1: dual bucket scatter | W1 -> Wt1
    k_scatter2<<<CHUNKS + WCONV_BLK, 256, 0, stream>>>(src, dst, pcnt, scnt,
                                                       pbuf, sbuf, W1, Wt1);
    // K2: boff scan | src counts -> onorm
    k_scan_onorm<<<1 + NBUK, 256, 0, stream>>>(pcnt, boff, scnt, sbuf, onorm);
    // K3: per-bucket CSR finalize | embed (+onorm prescale)
    k_bsort_embed<<<NBUK + EMB_BLK1K, 1024, 0, stream>>>(pbuf, boff, colidx, rowptr, inorm,
                                                         feature, emb, onorm, hA);

    const int aggGrid = (NN * 64 + 255) / 256;
    const int gemmGrid = (NN + 383) / 384;
    // layer 0 (no W): hB = relu(agg(hA) * inorm) * onorm
    k_agg<0><<<aggGrid, 256, 0, stream>>>(rowptr, colidx, hA, inorm, onorm, hB);
    // layer 1: hA = hB @ W1 ; hB = relu(agg(hA) * inorm) * onorm
    k_gemm<<<gemmGrid, 512, 0, stream>>>(hB, Wt1, hA);
    k_agg<0><<<aggGrid, 256, 0, stream>>>(rowptr, colidx, hA, inorm, onorm, hB);
    // layer 2 (W2 hoisted past agg+pool by linearity): hA = agg(hB) * inorm
    k_agg<1><<<aggGrid, 256, 0, stream>>>(rowptr, colidx, hB, inorm, onorm, hA);
    // P = pool(hA) ; out = P @ W2
    k_pool<<<NG, 256, 0, stream>>>(hA, gids, Pbuf);
    k_pgemm<<<NG / 8, 256, 0, stream>>>(Pbuf, W2, out);
}